// Round 12
// baseline (65.817 us; speedup 1.0000x reference)
//
#include <hip/hip_runtime.h>

// Problem constants
#define TT   512
#define BB   32
#define TS_F 76
#define N_WF 200
#define WF_LEN 1000
#define TEXT_D 200
#define WF_D 100
#define HID  256
#define FC_H 256
#define ROWS (TT*BB)              // 16384
#define K1REAL 556

// K-order for s4: [0,200) texts | [200,224) zeros | [224,608) feat2 (fc=k-224)
// chunks 0..6 texts (global pipeline), 7..14 ts_out (LDS), 15..18 spread (LDS)
#define K4_NCH  19
#define K4T_NCH 7                 // texts chunks

// ---- fragment-packed B geometry (pre-split hi/lo, MFMA 16x16x32 layout)
#define S1_NJ     7                       // 112 cols (100 real)
#define WWF_STEP  (S1_NJ*1024)            // 7168 shorts per K-step
#define WWF_TOT   (32*WWF_STEP)           // 229376
#define S2_NSTEP  3                       // K = 96 (76 real)
#define WTS_STEP  (16*1024)
#define WTS_TOT   (S2_NSTEP*WTS_STEP)     // 49152
#define W1F_STEP  (16*1024)
#define W1F_TOT   (K4_NCH*W1F_STEP)       // 311296
#define K3_NSTEP  7                       // K = 224 (200 real)
#define K3_NJ     8                       // 128 cols (100 real)
#define WFO3_PER_B (K3_NSTEP*K3_NJ*1024)  // 57344 shorts per batch b
#define WFO3_TOT  (BB*WFO3_PER_B)         // 1835008

// s1 split-K partials: partT[z][bb][c(112)][n(224)] f32
#define S1_Z      4
#define PART_C    112
#define PART_N    224
#define PART_PER_Z (BB*PART_C*PART_N)     // 802816 f32

typedef __attribute__((ext_vector_type(8))) short short8;
typedef __attribute__((ext_vector_type(4))) short sshort4;
typedef __attribute__((ext_vector_type(4))) float f32x4;

// Truncating bf16 split: hi = v low-16-zeroed (exact subtraction), lo = residual.
__device__ __forceinline__ void split_bf16(float v, short& h, short& l) {
    unsigned u = __builtin_bit_cast(unsigned, v);
    unsigned hu = u & 0xFFFF0000u;
    h = (short)(hu >> 16);
    float r = v - __builtin_bit_cast(float, hu);
    l = (short)(__builtin_bit_cast(unsigned, r) >> 16);
}

// direct A-fragment loader: lane supplies A[row][k0..k0+7], guarded, split
__device__ __forceinline__ void loadA_frag(const float* __restrict__ rowp,
                                           int k0, int kreal,
                                           short8& a_h, short8& a_l) {
    float va[8];
    if (k0 + 8 <= kreal) {
        float4 t0 = ((const float4*)(rowp + k0))[0];
        float4 t1 = ((const float4*)(rowp + k0))[1];
        va[0]=t0.x; va[1]=t0.y; va[2]=t0.z; va[3]=t0.w;
        va[4]=t1.x; va[5]=t1.y; va[6]=t1.z; va[7]=t1.w;
    } else {
        #pragma unroll
        for (int q = 0; q < 8; q++) va[q] = (k0 + q < kreal) ? rowp[k0 + q] : 0.f;
    }
    #pragma unroll
    for (int q = 0; q < 8; q++) { short h, s; split_bf16(va[q], h, s); a_h[q]=h; a_l[q]=s; }
}

// ============ K0: packs needed by K1/K4 ====================================
__global__ __launch_bounds__(256)
void k0_prep(const float* __restrict__ W_wf, const float* __restrict__ W_ts,
             short* __restrict__ wwfF, short* __restrict__ wtsF)
{
    const int b = blockIdx.x, tid = threadIdx.x;
    if (b < 56) {                       // wwf: 32 steps x 7 tiles x 64 lanes
        int idx = b*256 + tid;          // [0,14336)
        int l = idx & 63;
        int t = idx >> 6;               // 0..223
        int jt = t % 7, st = t / 7;
        int c = jt*16 + (l & 15), lq = l >> 4;
        short8 h8, l8;
        #pragma unroll
        for (int q = 0; q < 8; q++) {
            int k = st*32 + lq*8 + q;
            float v = (k < WF_LEN && c < WF_D) ? W_wf[k*WF_D + c] : 0.f;
            short h, s; split_bf16(v, h, s); h8[q]=h; l8[q]=s;
        }
        int off = (st*7 + jt)*1024 + l*8;
        *(short8*)(wwfF + off)       = h8;
        *(short8*)(wwfF + off + 512) = l8;
    } else {                            // wts: 3 steps x 16 tiles x 64 lanes
        int idx = (b-56)*256 + tid;     // [0,3072)
        int l = idx & 63, jj = (idx>>6) & 15, st = idx >> 10;
        int c = jj*16 + (l&15), lq = l >> 4;
        short8 h8, l8;
        #pragma unroll
        for (int q = 0; q < 8; q++) {
            int k = st*32 + lq*8 + q;
            float v = (k < TS_F) ? W_ts[k*HID + c] : 0.f;
            short h, s; split_bf16(v, h, s); h8[q]=h; l8[q]=s;
        }
        int off = (st*16 + jj)*1024 + l*8;
        *(short8*)(wtsF + off)       = h8;
        *(short8*)(wtsF + off + 512) = l8;
    }
}

// ============ K1: s1 only (barrier-free, LDS-free, direct-A) ===============
// 400 blocks: 64 rows x 112 cols, K-slice of 256 (8 steps) -> partT[z][bb][c][n]
__global__ __launch_bounds__(256)
void k1_main(const float* __restrict__ wf, const short* __restrict__ wwfF,
             float* __restrict__ partT)
{
    const int b = blockIdx.x, tid = threadIdx.x;
    const int wv = tid >> 6, lane = tid & 63;
    const int m16 = lane & 15, quad = lane >> 4;

    const int by = b % 100, z = b / 100;
    const int row0 = by * 64;
    const float* rowp = wf + (long long)(row0 + wv*16 + m16) * WF_LEN;
    const int kb = z * 256 + quad * 8;

    f32x4 acc[7];
    #pragma unroll
    for (int j = 0; j < 7; j++) acc[j] = f32x4{0.f, 0.f, 0.f, 0.f};

    #pragma unroll 2
    for (int cl = 0; cl < 8; ++cl) {
        short8 a_h, a_l;
        loadA_frag(rowp, kb + cl*32, WF_LEN, a_h, a_l);

        const short* fb = wwfF + (z*8 + cl) * WWF_STEP + lane * 8;
        short8 bh[7], bl[7];
        #pragma unroll
        for (int j = 0; j < 7; j++) {
            bh[j] = *(const short8*)(fb + j * 1024);
            bl[j] = *(const short8*)(fb + j * 1024 + 512);
        }
        #pragma unroll
        for (int j = 0; j < 7; j++) {
            acc[j] = __builtin_amdgcn_mfma_f32_16x16x32_bf16(a_h, bh[j], acc[j], 0, 0, 0);
            acc[j] = __builtin_amdgcn_mfma_f32_16x16x32_bf16(a_h, bl[j], acc[j], 0, 0, 0);
            acc[j] = __builtin_amdgcn_mfma_f32_16x16x32_bf16(a_l, bh[j], acc[j], 0, 0, 0);
        }
    }

    // f32 partial store (float4, disjoint per z -> deterministic)
    float* Cb = partT + (long long)z * PART_PER_Z;
    const int r = row0 + wv*16 + quad*4;          // 4-aligned, never crosses bb
    const int bb2 = r / N_WF, n = r - bb2 * N_WF;
    #pragma unroll
    for (int j = 0; j < 7; j++) {
        int cc = j * 16 + m16;
        if (cc >= WF_D) continue;
        float4 t;
        t.x = acc[j][0]; t.y = acc[j][1]; t.z = acc[j][2]; t.w = acc[j][3];
        *(float4*)&Cb[((long long)bb2 * PART_C + cc) * PART_N + n] = t;
    }
}

// ---- K2: reduce z-slices -> wfo3F frag layout + w1F pack ------------------
__global__ __launch_bounds__(256)
void k2_reduce(const float* __restrict__ partT, const float* __restrict__ b_wf,
               const float* __restrict__ W1,
               short* __restrict__ wfo3F, short* __restrict__ w1F)
{
    const int blk = blockIdx.x, tid = threadIdx.x;
    if (blk < 448) {
        const int bb = blk / 14, rem = blk % 14;
        const int st = rem >> 1, half = rem & 1;
        const int j = half * 4 + (tid >> 6);
        const int g = tid & 63;
        const int m16 = g & 15, kk8 = g >> 4;
        const int c = j * 16 + m16;
        const int n = st * 32 + kk8 * 8;

        float v[8];
        if (c < WF_D && n < N_WF) {
            float bw = b_wf[c];
            #pragma unroll
            for (int q = 0; q < 8; q++) v[q] = bw;
            #pragma unroll
            for (int z = 0; z < S1_Z; z++) {
                const float* p = partT + (long long)z * PART_PER_Z
                               + ((long long)bb * PART_C + c) * PART_N + n;
                float4 t0 = ((const float4*)p)[0];
                float4 t1 = ((const float4*)p)[1];
                v[0]+=t0.x; v[1]+=t0.y; v[2]+=t0.z; v[3]+=t0.w;
                v[4]+=t1.x; v[5]+=t1.y; v[6]+=t1.z; v[7]+=t1.w;
            }
        } else {
            #pragma unroll
            for (int q = 0; q < 8; q++) v[q] = 0.f;
        }
        short8 h8, l8;
        #pragma unroll
        for (int q = 0; q < 8; q++) { short h, s; split_bf16(v[q], h, s); h8[q]=h; l8[q]=s; }
        long long base = (long long)bb * WFO3_PER_B + st * (K3_NJ*1024) + j * 1024 + g * 8;
        *(short8*)(wfo3F + base)       = h8;
        *(short8*)(wfo3F + base + 512) = l8;
    } else {                            // w1F pack: 19 chunks x 16 tiles x 64 lanes
        int idx = (blk-448)*256 + tid;  // [0,19456)
        int l = idx & 63, t = idx >> 6;
        int jj = t & 15, ch = t >> 4;
        int n = jj*16 + (l&15), lq = l >> 4;
        short8 h8, l8;
        #pragma unroll
        for (int q = 0; q < 8; q++) {
            int k = ch*32 + lq*8 + q;    // K-order index [0,608)
            float v = 0.f;
            if (k < 200)                  v = W1[k*FC_H + n];
            else if (k >= 224 && k < 580) v = W1[(k-24)*FC_H + n];
            short h, s; split_bf16(v, h, s); h8[q]=h; l8[q]=s;
        }
        int off = (ch*16 + jj)*1024 + l*8;
        *(short8*)(w1F + off)       = h8;
        *(short8*)(w1F + off + 512) = l8;
    }
}

// ====== K4 fused v3: phase A = s3 spread (64x128) + s2 ts_out (64x256)
//   computed in-block, deposited in LDS A-frag slots 0..11; phase B = texts
//   chunks 0..6 (R10 pipeline) then chunks 7..18 barrier-free from LDS;
//   atomic-free LDS cross-wave reduction head epilogue. =====================
__global__ __launch_bounds__(512)
void k4_fused(const float* __restrict__ wwm, const float* __restrict__ ts,
              const float* __restrict__ texts,
              const short* __restrict__ wfo3F, const short* __restrict__ wtsF,
              const short* __restrict__ w1F,
              const float* __restrict__ b_ts, const float* __restrict__ b1,
              const float* __restrict__ W2, const float* __restrict__ b2,
              float* __restrict__ out)
{
    __shared__ short AhB[2][2048], AlB[2][2048];   // 16 KB texts A dbuf
    __shared__ short fLH[12][2048], fLL[12][2048]; // 96 KB feat A-frag slots
    __shared__ float transF[64*132];               // 33.8 KB transpose buf
    __shared__ float ored[8][64][2];               // 4 KB cross-wave reduce

    const int tid = threadIdx.x;
    const int wv = tid >> 6, lane = tid & 63;
    const int m16 = lane & 15, quad = lane >> 4;
    const int rt = blockIdx.x;
    const int row0 = rt * 64;
    const int fsw = (quad ^ ((m16 >> 1) & 3)) * 8;

    // frag-build helper: transF [64 rows][128 cols] -> fL slots base..base+3
    auto buildFrags = [&](int base) {
        #pragma unroll
        for (int i = 0; i < 2; i++) {
            int slot = tid*2 + i;               // [0,1024)
            int l = slot & 63, ri = (slot >> 6) & 3, cf = slot >> 8;
            int lrow = l & 15, cg = l >> 4;
            const float* p = &transF[(ri*16 + lrow)*132 + cf*32 + cg*8];
            short8 h8, l8;
            #pragma unroll
            for (int q = 0; q < 8; q++) { short h, s; split_bf16(p[q], h, s); h8[q]=h; l8[q]=s; }
            *(short8*)&fLH[base + cf][(ri << 9) + l*8] = h8;
            *(short8*)&fLL[base + cf][(ri << 9) + l*8] = l8;
        }
    };

    // ---------------- Phase A1: s3 spread (64 x 128) -----------------------
    const int bz = rt >> 3, by = rt & 7;
    const int bx3 = wv >> 2, wrow = wv & 3;
    {
        const float* rowp3 = wwm + ((long long)bz * TT + by*64 + wrow*16 + m16) * N_WF;
        const short* FB = wfo3F + (long long)bz * WFO3_PER_B;

        f32x4 acc3[4];
        #pragma unroll
        for (int j = 0; j < 4; j++) acc3[j] = f32x4{0.f, 0.f, 0.f, 0.f};

        #pragma unroll 2
        for (int st = 0; st < K3_NSTEP; ++st) {
            short8 a_h, a_l;
            loadA_frag(rowp3, st*32 + quad*8, N_WF, a_h, a_l);
            const short* fb = FB + st * (K3_NJ*1024) + (bx3*4) * 1024 + lane * 8;
            #pragma unroll
            for (int j = 0; j < 4; j++) {
                short8 b_h = *(const short8*)(fb + j * 1024);
                short8 b_l = *(const short8*)(fb + j * 1024 + 512);
                acc3[j] = __builtin_amdgcn_mfma_f32_16x16x32_bf16(a_h, b_h, acc3[j], 0, 0, 0);
                acc3[j] = __builtin_amdgcn_mfma_f32_16x16x32_bf16(a_h, b_l, acc3[j], 0, 0, 0);
                acc3[j] = __builtin_amdgcn_mfma_f32_16x16x32_bf16(a_l, b_h, acc3[j], 0, 0, 0);
            }
        }
        // spread -> transF (cols >= 100 are zeros via wfo3F pad) -> slots 8..11
        #pragma unroll
        for (int j = 0; j < 4; j++)
            #pragma unroll
            for (int rr = 0; rr < 4; rr++)
                transF[(wrow*16 + quad*4 + rr)*132 + bx3*64 + j*16 + m16] =
                    acc3[j][rr] * (1.0f / N_WF);
    }
    __syncthreads();
    buildFrags(8);

    // ---------------- Phase A2: s2 ts_out (64 x 256) -----------------------
    {
        const int rg = wv & 3, ch2 = wv >> 2;     // row-group, col-half
        const float* rowp2 = ts + (long long)(row0 + rg*16 + m16) * TS_F;

        f32x4 acc2[8];
        #pragma unroll
        for (int j = 0; j < 8; j++) acc2[j] = f32x4{0.f, 0.f, 0.f, 0.f};

        #pragma unroll
        for (int st = 0; st < S2_NSTEP; ++st) {
            short8 a_h, a_l;
            loadA_frag(rowp2, st*32 + quad*8, TS_F, a_h, a_l);
            const short* fb0 = wtsF + st * WTS_STEP + (ch2*8) * 1024 + lane * 8;
            #pragma unroll
            for (int j = 0; j < 8; j++) {
                short8 b_h = *(const short8*)(fb0 + j * 1024);
                short8 b_l = *(const short8*)(fb0 + j * 1024 + 512);
                acc2[j] = __builtin_amdgcn_mfma_f32_16x16x32_bf16(a_h, b_h, acc2[j], 0, 0, 0);
                acc2[j] = __builtin_amdgcn_mfma_f32_16x16x32_bf16(a_h, b_l, acc2[j], 0, 0, 0);
                acc2[j] = __builtin_amdgcn_mfma_f32_16x16x32_bf16(a_l, b_h, acc2[j], 0, 0, 0);
            }
        }

        // two passes: cols 0..127 (ch2==0 waves), then 128..255 (ch2==1)
        #pragma unroll
        for (int p = 0; p < 2; p++) {
            __syncthreads();                      // transF free (prev build done)
            if (ch2 == p) {
                #pragma unroll
                for (int j = 0; j < 8; j++) {
                    float bv = b_ts[p*128 + j*16 + m16];
                    #pragma unroll
                    for (int rr = 0; rr < 4; rr++)
                        transF[(rg*16 + quad*4 + rr)*132 + j*16 + m16] =
                            tanhf(acc2[j][rr] + bv);
                }
            }
            __syncthreads();
            buildFrags(p * 4);                    // slots 0..3 then 4..7
        }
    }
    __syncthreads();

    // ---------------- Phase B: texts chunks 0..6 (R10 pipeline) ------------
    const int ar  = tid >> 2;
    const int ag  = tid & 3;
    const int asw = (ag ^ ((ar >> 1) & 3)) * 8;
    const long long gr = row0 + ar;

    f32x4 acc[4][2];
    #pragma unroll
    for (int i = 0; i < 4; i++)
        #pragma unroll
        for (int j = 0; j < 2; j++) acc[i][j] = f32x4{0.f, 0.f, 0.f, 0.f};

    float  vaP[8], vaQ[8];
    short8 vbhP[2], vblP[2], vbhQ[2], vblQ[2];

    auto loadTexts = [&](int c, float* va) {
        if (tid < 256) {
            int kc = c * 32 + ag * 8;
            if (kc + 8 <= TEXT_D) {
                const float4* p = (const float4*)(texts + gr * TEXT_D + kc);
                float4 t0 = p[0], t1 = p[1];
                va[0]=t0.x; va[1]=t0.y; va[2]=t0.z; va[3]=t0.w;
                va[4]=t1.x; va[5]=t1.y; va[6]=t1.z; va[7]=t1.w;
            } else {
                #pragma unroll
                for (int q = 0; q < 8; q++) va[q] = 0.f;
            }
        }
    };
    auto storeTexts = [&](const float* va, int buf) {
        if (tid < 256) {
            short8 h8, l8;
            #pragma unroll
            for (int q = 0; q < 8; q++) { short h, s; split_bf16(va[q], h, s); h8[q]=h; l8[q]=s; }
            *(short8*)&AhB[buf][ar*32 + asw] = h8;
            *(short8*)&AlB[buf][ar*32 + asw] = l8;
        }
    };
    auto loadB2 = [&](int c, short8* bh, short8* bl) {
        #pragma unroll
        for (int ci = 0; ci < 2; ci++) {
            const short* fb = w1F + (c * 16 + wv * 2 + ci) * 1024 + lane * 8;
            bh[ci] = *(const short8*)fb;
            bl[ci] = *(const short8*)(fb + 512);
        }
    };
    auto mfmaTexts = [&](int buf, const short8 bh[2], const short8 bl[2]) {
        short8 a_h[4], a_l[4];
        #pragma unroll
        for (int ri = 0; ri < 4; ri++) {
            a_h[ri] = *(const short8*)&AhB[buf][(ri*16 + m16)*32 + fsw];
            a_l[ri] = *(const short8*)&AlB[buf][(ri*16 + m16)*32 + fsw];
        }
        #pragma unroll
        for (int ci = 0; ci < 2; ci++)
            #pragma unroll
            for (int ri = 0; ri < 4; ri++) {
                acc[ri][ci] = __builtin_amdgcn_mfma_f32_16x16x32_bf16(a_h[ri], bh[ci], acc[ri][ci], 0, 0, 0);
                acc[ri][ci] = __builtin_amdgcn_mfma_f32_16x16x32_bf16(a_h[ri], bl[ci], acc[ri][ci], 0, 0, 0);
                acc[ri][ci] = __builtin_amdgcn_mfma_f32_16x16x32_bf16(a_l[ri], bh[ci], acc[ri][ci], 0, 0, 0);
            }
    };

    // prologue: chunks 0 (P) and 1 (Q) in flight; chunk 0 staged
    loadTexts(0, vaP); loadB2(0, vbhP, vblP);
    loadTexts(1, vaQ); loadB2(1, vbhQ, vblQ);
    storeTexts(vaP, 0);
    __syncthreads();

    for (int c = 0; c < K4T_NCH; c += 2) {
        // even chunk c (buf 0)
        {
            short8 bh[2] = {vbhP[0], vbhP[1]};
            short8 bl[2] = {vblP[0], vblP[1]};
            if (c + 2 < K4T_NCH) { loadTexts(c + 2, vaP); loadB2(c + 2, vbhP, vblP); }
            mfmaTexts(0, bh, bl);
            if (c + 1 < K4T_NCH) { storeTexts(vaQ, 1); __syncthreads(); }
        }
        // odd chunk c+1 (buf 1)
        if (c + 1 < K4T_NCH) {
            short8 bh[2] = {vbhQ[0], vbhQ[1]};
            short8 bl[2] = {vblQ[0], vblQ[1]};
            if (c + 3 < K4T_NCH) { loadTexts(c + 3, vaQ); loadB2(c + 3, vbhQ, vblQ); }
            mfmaTexts(1, bh, bl);
            if (c + 2 < K4T_NCH) { storeTexts(vaP, 0); __syncthreads(); }
        }
    }

    // chunks 7..18: A from LDS frag slots, barrier-free; B one-deep prefetch
    {
        short8 nbh[2], nbl[2];
        loadB2(7, nbh, nbl);
        for (int c = 7; c < 19; ++c) {
            short8 bh[2] = {nbh[0], nbh[1]};
            short8 bl[2] = {nbl[0], nbl[1]};
            if (c + 1 < 19) loadB2(c + 1, nbh, nbl);
            const int f = c - 7;
            short8 a_h[4], a_l[4];
            #pragma unroll
            for (int ri = 0; ri < 4; ri++) {
                a_h[ri] = *(const short8*)&fLH[f][ri*512 + lane*8];
                a_l[ri] = *(const short8*)&fLL[f][ri*512 + lane*8];
            }
            #pragma unroll
            for (int ci = 0; ci < 2; ci++)
                #pragma unroll
                for (int ri = 0; ri < 4; ri++) {
                    acc[ri][ci] = __builtin_amdgcn_mfma_f32_16x16x32_bf16(a_h[ri], bh[ci], acc[ri][ci], 0, 0, 0);
                    acc[ri][ci] = __builtin_amdgcn_mfma_f32_16x16x32_bf16(a_h[ri], bl[ci], acc[ri][ci], 0, 0, 0);
                    acc[ri][ci] = __builtin_amdgcn_mfma_f32_16x16x32_bf16(a_l[ri], bh[ci], acc[ri][ci], 0, 0, 0);
                }
        }
    }

    // epilogue: relu + head partials, per-wave 16-lane reduce, LDS cross-wave
    float o0[4][4] = {}, o1[4][4] = {};
    #pragma unroll
    for (int ci = 0; ci < 2; ci++) {
        int C = wv * 32 + ci * 16 + m16;
        float bv  = b1[C];
        float w20 = W2[C * 2 + 0];
        float w21 = W2[C * 2 + 1];
        #pragma unroll
        for (int ri = 0; ri < 4; ri++)
            #pragma unroll
            for (int rr = 0; rr < 4; rr++) {
                float v = fmaxf(acc[ri][ci][rr] + bv, 0.f);
                o0[ri][rr] += v * w20;
                o1[ri][rr] += v * w21;
            }
    }
    __syncthreads();
    #pragma unroll
    for (int ri = 0; ri < 4; ri++)
        #pragma unroll
        for (int rr = 0; rr < 4; rr++) {
            float s0 = o0[ri][rr], s1 = o1[ri][rr];
            #pragma unroll
            for (int mk = 1; mk < 16; mk <<= 1) {
                s0 += __shfl_xor(s0, mk);
                s1 += __shfl_xor(s1, mk);
            }
            if (m16 == 0) {
                int rl = ri * 16 + quad * 4 + rr;
                ored[wv][rl][0] = s0;
                ored[wv][rl][1] = s1;
            }
        }
    __syncthreads();
    if (tid < 128) {
        int rl = tid >> 1, cc = tid & 1;
        float s = b2[cc];
        #pragma unroll
        for (int w = 0; w < 8; w++) s += ored[w][rl][cc];
        out[(long long)(row0 + rl) * 2 + cc] = s;
    }
}

extern "C" void kernel_launch(void* const* d_in, const int* in_sizes, int n_in,
                              void* d_out, int out_size, void* d_ws, size_t ws_size,
                              hipStream_t stream)
{
    const float* texts = (const float*)d_in[0];   // (512,32,200)
    const float* ts    = (const float*)d_in[1];   // (512,32,76)
    const float* wf    = (const float*)d_in[2];   // (32,200,1000)
    const float* wwm   = (const float*)d_in[3];   // (32,512,200)
    const float* W_wf  = (const float*)d_in[4];   // (1000,100)
    const float* b_wf  = (const float*)d_in[5];
    const float* W_ts  = (const float*)d_in[6];   // (76,256)
    const float* b_ts  = (const float*)d_in[7];
    const float* W1    = (const float*)d_in[8];   // (556,256)
    const float* b1    = (const float*)d_in[9];
    const float* W2    = (const float*)d_in[10];  // (256,2)
    const float* b2    = (const float*)d_in[11];
    float* out = (float*)d_out;

    // ---- workspace layout (all disjoint, ~18 MB) ----
    float* partT  = (float*)d_ws;                      // 4*802816 f32
    short* wwfF   = (short*)(partT + S1_Z * PART_PER_Z);
    short* wtsF   = wwfF + WWF_TOT;
    short* w1F    = wtsF + WTS_TOT;
    short* wfo3F  = w1F + W1F_TOT;

    // 0) weight packs (wwfF for k1, wtsF for k4)
    k0_prep<<<68, 256, 0, stream>>>(W_wf, W_ts, wwfF, wtsF);

    // 1) s1 split-K partials (barrier-free, LDS-free)
    k1_main<<<400, 256, 0, stream>>>(wf, wwfF, partT);

    // 2) reduce -> wfo3F frag layout + w1F pack
    k2_reduce<<<524, 256, 0, stream>>>(partT, b_wf, W1, wfo3F, w1F);

    // 3) fused s2 + s3 + s4 + head
    k4_fused<<<ROWS / 64, 512, 0, stream>>>(wwm, ts, texts, wfo3F, wtsF,
                                            w1F, b_ts, b1, W2, b2, out);
}